// Round 14
// baseline (259.223 us; speedup 1.0000x reference)
//
#include <hip/hip_runtime.h>

#define MAXLEN 100
#define HDIM 64
#define CH 4                       // x-staging chunk length (steps)
#define NSEG 32                    // segments per block: 2 MFMA row-tiles, all real
#define SROW 72                    // ushorts per bf16 x step-row (144 B)
#define SPLANE (CH * SROW + 8)     // 296 ushorts per segment plane
#define HSTR 72                    // ushorts per h row (144 B)
#define L2E 1.44269504f

typedef __attribute__((ext_vector_type(8))) short bf16x8;
typedef __attribute__((ext_vector_type(4))) float f32x4;

// Step barrier: LDS-only consistency (no implicit vmcnt(0) drain), so the
// chunk-ahead x prefetch stays in flight across all step barriers.
#define LGKM_BARRIER() asm volatile("s_waitcnt lgkmcnt(0)\n\ts_barrier" ::: "memory")

// RNE f32x2 -> packed bf16x2 in one instruction (no builtin on gfx950).
__device__ __forceinline__ unsigned cvtpk(float a, float b) {
    unsigned r;
    asm("v_cvt_pk_bf16_f32 %0, %1, %2" : "=v"(r) : "v"(a), "v"(b));
    return r;
}
__device__ __forceinline__ bf16x8 pack8(f32x4 a, f32x4 b) {
    union { unsigned u[4]; bf16x8 v; } c;
    c.u[0] = cvtpk(a[0], a[1]); c.u[1] = cvtpk(a[2], a[3]);
    c.u[2] = cvtpk(b[0], b[1]); c.u[3] = cvtpk(b[2], b[3]);
    return c.v;
}
// Activations on PRE-SCALED pre-activations: -L2E (resp -2*L2E for gate g)
// is folded into the bf16 weights; the scaled bias is the MFMA C-seed.
__device__ __forceinline__ float sig_pre(float a) {     // a = -L2E*z
    return __builtin_amdgcn_rcpf(1.0f + __builtin_amdgcn_exp2f(a));
}
__device__ __forceinline__ float tanh_pre(float a) {    // a = -2*L2E*z
    return fmaf(2.0f, __builtin_amdgcn_rcpf(1.0f + __builtin_amdgcn_exp2f(a)), -1.0f);
}
__device__ __forceinline__ float tanh_p(float v) {      // v in true scale
    return fmaf(2.0f, __builtin_amdgcn_rcpf(1.0f + __builtin_amdgcn_exp2f(v * (-2.0f * L2E))), -1.0f);
}

// SINGLE-DISPATCH kernel. NSEG=32 -> 256 blocks = exactly 1 block/CU.
// R13's snake-null showed per-step wall is dominated by the INTRA-block
// critical path, not cross-block contention; at 1 block/CU the length-sort
// is therefore useless (wall = global-lmax x solo-step-wall regardless of
// grouping) -> the whole 2-kernel pre-pass chain (~20us of node overhead)
// is DELETED. Per-block segment bounds via in-kernel binary search
// (R0-verified pattern).
//
// Structure: 4 waves x 256 threads; wave w owns hidden cols [16w,16w+16) for
// all 4 gates. 32 segments = TWO 16-row MFMA A/C tiles (all rows real):
// tile0 = segs 0..15 (A-row l15), tile1 = segs 16..31. Per step per wave:
// 16 h-MFMAs + 16 x-MFMAs (next step, in trans shadow) + 8 gate cells/lane.
// Machine-wide per-step work identical to NSEG=16 @ 2 blocks/CU, but ONE
// barrier domain per CU (no cross-block interference, less skew).
// Per-step MFMA chain split: accx = x_t @ Wih' (bias-seeded, h-independent)
// computed in the previous step's trans shadow; serial step is
// acc = mfma(ha1,wh1, mfma(ha0,wh0,accx)).
__global__ __launch_bounds__(256, 1)
void lstm32_kernel(const float* __restrict__ x,
                   const float* __restrict__ Wih,
                   const float* __restrict__ Whh,
                   const float* __restrict__ bih,
                   const float* __restrict__ bhh,
                   const int* __restrict__ index,
                   float* __restrict__ out, int N, int B) {
    const int tid  = threadIdx.x;
    const int w    = tid >> 6;
    const int lane = tid & 63;
    const int l15  = lane & 15;
    const int quad = lane >> 4;
    const int segbase = blockIdx.x * NSEG;
    const int ncol = w * 16 + l15;

    __shared__ __align__(16) unsigned short xst[NSEG * SPLANE];  // 18.9 KB
    __shared__ __align__(16) unsigned short hst[2][NSEG][HSTR];  // 9.2 KB
    __shared__ int sstart[NSEG], slen[NSEG], sseg[NSEG];

    // --- per-block segment bounds: 32 threads x dual binary search ---
    if (tid < NSEG) {
        const int b = segbase + tid;
        int sg = -1, s = 0, len = 0;
        if (b < B) {
            sg = b;
            int lo = 0, hi = N;
            while (lo < hi) { int m = (lo + hi) >> 1; if (index[m] < b) lo = m + 1; else hi = m; }
            s = lo;
            hi = N;
            while (lo < hi) { int m = (lo + hi) >> 1; if (index[m] < b + 1) lo = m + 1; else hi = m; }
            len = lo - s;
            len = len < MAXLEN ? len : MAXLEN;
        }
        sstart[tid] = s;
        slen[tid] = len;
        sseg[tid] = sg;
    }
    for (int i = tid; i < 2 * NSEG * HSTR / 2; i += 256) ((int*)hst)[i] = 0;
    __syncthreads();

    // --- weight B-fragments (register-resident), PRE-SCALED by the exp2
    // factor; scaled bias becomes the per-gate MFMA C-seed bsv[g]. ---
    bf16x8 wi[4][2], wh[4][2];
    f32x4 bsv[4];
#pragma unroll
    for (int g = 0; g < 4; ++g) {
        const float sc = (g == 2) ? (-2.0f * L2E) : (-L2E);
        const int row = g * HDIM + ncol;
        const float bb = sc * (bih[row] + bhh[row]);
        bsv[g][0] = bb; bsv[g][1] = bb; bsv[g][2] = bb; bsv[g][3] = bb;
#pragma unroll
        for (int kt = 0; kt < 2; ++kt) {
            const f32x4* pi = (const f32x4*)(Wih + (size_t)row * HDIM + kt * 32 + quad * 8);
            const f32x4* ph = (const f32x4*)(Whh + (size_t)row * HDIM + kt * 32 + quad * 8);
            wi[g][kt] = pack8(pi[0] * sc, pi[1] * sc);
            wh[g][kt] = pack8(ph[0] * sc, ph[1] * sc);
        }
    }

    // Per-lane gate-math metadata: tile0 segs quad*4+r, tile1 segs 16+quad*4+r.
    int lenA[4], lenB[4];
#pragma unroll
    for (int r = 0; r < 4; ++r) {
        lenA[r] = slen[quad * 4 + r];
        lenB[r] = slen[16 + quad * 4 + r];
    }
    int lmax = 0;
#pragma unroll
    for (int i = 0; i < NSEG; ++i) { int v = slen[i]; lmax = v > lmax ? v : lmax; }
    lmax = __builtin_amdgcn_readfirstlane(lmax);

    // Staging roles: 32 segs x 4 steps x 4 col-groups = 512 units; each of
    // 256 threads stages TWO segs (sS and sS+16). pre0/pre1 = 32 VGPRs.
    const int sS = tid >> 4, sT = (tid >> 2) & 3, sC = tid & 3;
    const int sst0 = sstart[sS],      sln0 = slen[sS];
    const int sst1 = sstart[sS + 16], sln1 = slen[sS + 16];

    f32x4 pre0[4], pre1[4];

#define ISSUE(t0_)                                                              \
    {                                                                           \
        int ct0 = (t0_) + sT;                                                   \
        ct0 = (sln0 > 0) ? (ct0 < sln0 ? ct0 : sln0 - 1) : 0;                   \
        int row0 = sst0 + ct0; row0 = row0 < N - 1 ? row0 : N - 1;              \
        const f32x4* p_ = (const f32x4*)(x + (size_t)row0 * HDIM + sC * 16);    \
        pre0[0] = p_[0]; pre0[1] = p_[1]; pre0[2] = p_[2]; pre0[3] = p_[3];     \
        int ct1 = (t0_) + sT;                                                   \
        ct1 = (sln1 > 0) ? (ct1 < sln1 ? ct1 : sln1 - 1) : 0;                   \
        int row1 = sst1 + ct1; row1 = row1 < N - 1 ? row1 : N - 1;              \
        const f32x4* q_ = (const f32x4*)(x + (size_t)row1 * HDIM + sC * 16);    \
        pre1[0] = q_[0]; pre1[1] = q_[1]; pre1[2] = q_[2]; pre1[3] = q_[3];     \
    }
#define COMMIT()                                                                \
    {                                                                           \
        uint4 o1, o2;                                                           \
        o1.x = cvtpk(pre0[0][0], pre0[0][1]); o1.y = cvtpk(pre0[0][2], pre0[0][3]); \
        o1.z = cvtpk(pre0[1][0], pre0[1][1]); o1.w = cvtpk(pre0[1][2], pre0[1][3]); \
        o2.x = cvtpk(pre0[2][0], pre0[2][1]); o2.y = cvtpk(pre0[2][2], pre0[2][3]); \
        o2.z = cvtpk(pre0[3][0], pre0[3][1]); o2.w = cvtpk(pre0[3][2], pre0[3][3]); \
        unsigned short* d0_ = &xst[sS * SPLANE + sT * SROW + sC * 16];          \
        *(uint4*)d0_ = o1; *(uint4*)(d0_ + 8) = o2;                             \
        uint4 o3, o4;                                                           \
        o3.x = cvtpk(pre1[0][0], pre1[0][1]); o3.y = cvtpk(pre1[0][2], pre1[0][3]); \
        o3.z = cvtpk(pre1[1][0], pre1[1][1]); o3.w = cvtpk(pre1[1][2], pre1[1][3]); \
        o4.x = cvtpk(pre1[2][0], pre1[2][1]); o4.y = cvtpk(pre1[2][2], pre1[2][3]); \
        o4.z = cvtpk(pre1[3][0], pre1[3][1]); o4.w = cvtpk(pre1[3][2], pre1[3][3]); \
        unsigned short* d1_ = &xst[(sS + 16) * SPLANE + sT * SROW + sC * 16];   \
        *(uint4*)d1_ = o3; *(uint4*)(d1_ + 8) = o4;                             \
    }

    // x A-frag source planes: tile0 row l15 -> seg l15; tile1 -> seg 16+l15.
    const unsigned short* xb0 = &xst[l15 * SPLANE + quad * 8];
    const unsigned short* xb1 = &xst[(16 + l15) * SPLANE + quad * 8];

    // accx[tile][g] = bias + x_t @ Wih' for the upcoming step.
    f32x4 accx[2][4];
#define ACCX(tt_)                                                               \
    {                                                                           \
        const unsigned short* xr0_ = xb0 + (tt_) * SROW;                        \
        bf16x8 a0_ = *(const bf16x8*)(xr0_);                                    \
        bf16x8 a1_ = *(const bf16x8*)(xr0_ + 32);                               \
        const unsigned short* xr1_ = xb1 + (tt_) * SROW;                        \
        bf16x8 b0_ = *(const bf16x8*)(xr1_);                                    \
        bf16x8 b1_ = *(const bf16x8*)(xr1_ + 32);                               \
        _Pragma("unroll")                                                       \
        for (int g_ = 0; g_ < 4; ++g_) {                                        \
            f32x4 t0_ = __builtin_amdgcn_mfma_f32_16x16x32_bf16(a0_, wi[g_][0], bsv[g_], 0, 0, 0); \
            accx[0][g_] = __builtin_amdgcn_mfma_f32_16x16x32_bf16(a1_, wi[g_][1], t0_, 0, 0, 0); \
            f32x4 t1_ = __builtin_amdgcn_mfma_f32_16x16x32_bf16(b0_, wi[g_][0], bsv[g_], 0, 0, 0); \
            accx[1][g_] = __builtin_amdgcn_mfma_f32_16x16x32_bf16(b1_, wi[g_][1], t1_, 0, 0, 0); \
        }                                                                       \
    }

    float cA[4] = {0, 0, 0, 0}, hA[4] = {0, 0, 0, 0};
    float cB[4] = {0, 0, 0, 0}, hB[4] = {0, 0, 0, 0};
    const int nch = (lmax + CH - 1) / CH;

    if (nch > 0) {
        ISSUE(0);
        COMMIT();                      // compiler auto-waits vmcnt for pre use
        LGKM_BARRIER();
        ACCX(0);                       // x-part of step 0
        if (nch > 1) ISSUE(CH);        // chunk 1 in flight across chunk 0's steps

        for (int ch = 0; ch < nch; ++ch) {
            const int t0 = ch * CH;
#pragma unroll
            for (int tt = 0; tt < CH; ++tt) {
                const int t = t0 + tt;          // parity(t) == parity(tt), CH even
                const int pb = tt & 1, nb2 = pb ^ 1;

                // h-dependent half: 2-deep chains seeded by accx, both tiles.
                const unsigned short* hr0 = &hst[pb][l15][quad * 8];
                bf16x8 ha0 = *(const bf16x8*)(hr0);
                bf16x8 ha1 = *(const bf16x8*)(hr0 + 32);
                const unsigned short* hr1 = &hst[pb][16 + l15][quad * 8];
                bf16x8 hb0 = *(const bf16x8*)(hr1);
                bf16x8 hb1 = *(const bf16x8*)(hr1 + 32);

                f32x4 acc[2][4];
#pragma unroll
                for (int g = 0; g < 4; ++g) {
                    f32x4 a = __builtin_amdgcn_mfma_f32_16x16x32_bf16(ha0, wh[g][0], accx[0][g], 0, 0, 0);
                    acc[0][g] = __builtin_amdgcn_mfma_f32_16x16x32_bf16(ha1, wh[g][1], a, 0, 0, 0);
                    f32x4 b = __builtin_amdgcn_mfma_f32_16x16x32_bf16(hb0, wh[g][0], accx[1][g], 0, 0, 0);
                    acc[1][g] = __builtin_amdgcn_mfma_f32_16x16x32_bf16(hb1, wh[g][1], b, 0, 0, 0);
                }

                // x-part of the NEXT step (independent of h): fills the
                // MFMA pipe while this step's gate trans runs.
                if (tt + 1 < CH) ACCX(tt + 1);

                // Gate math: 8 real cells/lane (2 tiles x C regs 0..3).
                // acc is pre-scaled (incl bias) -> activations are fma-free.
#pragma unroll
                for (int r = 0; r < 4; ++r) {
                    float gi = sig_pre (acc[0][0][r]);
                    float gf = sig_pre (acc[0][1][r]);
                    float gg = tanh_pre(acc[0][2][r]);
                    float go = sig_pre (acc[0][3][r]);
                    float cn = fmaf(gf, cA[r], gi * gg);
                    float hn = go * tanh_p(cn);
                    const bool up = t < lenA[r];
                    cA[r] = up ? cn : cA[r];
                    hA[r] = up ? hn : hA[r];
                    hst[nb2][quad * 4 + r][ncol] = (unsigned short)cvtpk(hA[r], hA[r]);
                }
#pragma unroll
                for (int r = 0; r < 4; ++r) {
                    float gi = sig_pre (acc[1][0][r]);
                    float gf = sig_pre (acc[1][1][r]);
                    float gg = tanh_pre(acc[1][2][r]);
                    float go = sig_pre (acc[1][3][r]);
                    float cn = fmaf(gf, cB[r], gi * gg);
                    float hn = go * tanh_p(cn);
                    const bool up = t < lenB[r];
                    cB[r] = up ? cn : cB[r];
                    hB[r] = up ? hn : hB[r];
                    hst[nb2][16 + quad * 4 + r][ncol] = (unsigned short)cvtpk(hB[r], hB[r]);
                }
                LGKM_BARRIER();
            }
            if (ch + 1 < nch) {
                COMMIT();                          // chunk ch+1 (vmcnt auto-waited)
                LGKM_BARRIER();
                ACCX(0);                           // x-part of next chunk's step 0
                if (ch + 2 < nch) ISSUE((ch + 2) * CH);
            }
        }
    }

#pragma unroll
    for (int r = 0; r < 4; ++r) {
        const int sgA = sseg[quad * 4 + r];
        if (sgA >= 0) out[(size_t)sgA * HDIM + ncol] = hA[r];
        const int sgB = sseg[16 + quad * 4 + r];
        if (sgB >= 0) out[(size_t)sgB * HDIM + ncol] = hB[r];
    }
#undef ISSUE
#undef COMMIT
#undef ACCX
}

extern "C" void kernel_launch(void* const* d_in, const int* in_sizes, int n_in,
                              void* d_out, int out_size, void* d_ws, size_t ws_size,
                              hipStream_t stream) {
    const float* x   = (const float*)d_in[0];
    const float* Wih = (const float*)d_in[1];
    const float* Whh = (const float*)d_in[2];
    const float* bih = (const float*)d_in[3];
    const float* bhh = (const float*)d_in[4];
    const int* index = (const int*)d_in[5];

    const int N = in_sizes[5];
    const int B = out_size / HDIM;               // 8192
    const int nblocks = (B + NSEG - 1) / NSEG;   // 256 = 1 block/CU

    lstm32_kernel<<<nblocks, 256, 0, stream>>>(x, Wih, Whh, bih, bhh, index,
                                               (float*)d_out, N, B);
}